// Round 1
// baseline (483.115 us; speedup 1.0000x reference)
//
#include <hip/hip_runtime.h>

// Emformer mask materialization — compute-once / replicate-stores version.
//
// Structural fact exploited: within segment i, all 32 RC rows and all 128
// utterance rows have the IDENTICAL row image (reference builds rc_block and
// q_block from the same rc_vals); the summary row differs only by dropping
// the own-right-context interval. So each thread computes its ~11 column
// values once and stores them to 20 rows (4 RC + 16 Q) — ~20x less VALU per
// byte than the previous flat-index kernel, no integer division anywhere.
//
// Output dtype int32: 1 = attention disallowed, 0 = allowed.
namespace {
constexpr int SEG  = 128;   // segment_length
constexpr int RCL  = 32;    // right_context_length
constexpr int LC   = 64;    // left_context_length
constexpr int MEM  = 4;     // max_memory_length
constexpr int NSEG = 64;    // num_segments
constexpr int U    = NSEG * SEG;                    // 8192
constexpr int W    = (NSEG - 1) + RCL * NSEG + U;   // 10303 (mask width)
constexpr int RC_ROWS  = RCL * NSEG;                // 2048
constexpr int SUM_BASE = RC_ROWS + U;               // 10240
constexpr int UTT_BASE = (NSEG - 1) + RCL * NSEG;   // 2111

constexpr int COL_TILES  = 4;     // column tiles per row
constexpr int CPT        = 2576;  // columns per tile (last tile: 2575)
constexpr int ROW_GROUPS = 8;     // per segment: 4 RC rows + 16 Q rows each
constexpr int KMAX       = 11;    // ceil(CPT / 256)
}

__global__ __launch_bounds__(256) void emformer_mask_kernel(int* __restrict__ out) {
    const int tid = (int)threadIdx.x;
    const int rg  = (int)blockIdx.x;   // row group within segment, 0..7
    const int ct  = (int)blockIdx.y;   // column tile, 0..3
    const int i   = (int)blockIdx.z;   // segment index, 0..63

    const int colbase = ct * CPT;
    const int ncols   = min(CPT, W - colbase);   // 2576 (tiles 0-2) or 2575 (tile 3)

    // Allowed-column intervals for segment i.
    const int a0 = max(i - MEM, 0);              // memory slots [a0, a1)
    const int a1 = i;
    const int b0 = (NSEG - 1) + RCL * i;         // own right-context [b0, b0+RCL)
    const int d0 = UTT_BASE + max(SEG * i - LC, 0);  // own segment + left ctx [d0, d1)
    const int d1 = UTT_BASE + SEG * (i + 1);

    // Per-thread column values, computed once. vq: RC/utterance rows;
    // vs: summary row (no own-right-context interval).
    int vq[KMAX], vs[KMAX];
#pragma unroll
    for (int k = 0; k < KMAX; ++k) {
        const int c = colbase + tid + (k << 8);
        const bool inA = (unsigned)(c - a0) < (unsigned)(a1 - a0);
        const bool inB = (unsigned)(c - b0) < (unsigned)RCL;
        const bool inD = (unsigned)(c - d0) < (unsigned)(d1 - d0);
        vq[k] = (inA | inB | inD) ? 0 : 1;       // logical_not(allowed)
        vs[k] = (inA | inD) ? 0 : 1;
    }

    // Columns colbase + tid + 256k are in-bounds for all k < KMAX-1
    // (255 + 2304 = 2559 < 2575); only the last k needs a tail predicate.
    const bool has_tail = tid < (ncols - (KMAX - 1) * 256);   // tid < 16 (or 15)

    int* __restrict__ p = out + (size_t)colbase + tid;

    // 4 RC rows of this segment owned by this row group.
    {
        const int r0 = RCL * i + rg * 4;
        for (int rr = 0; rr < 4; ++rr) {
            int* __restrict__ rowp = p + (size_t)(r0 + rr) * W;
#pragma unroll
            for (int k = 0; k < KMAX - 1; ++k) rowp[k << 8] = vq[k];
            if (has_tail) rowp[(KMAX - 1) << 8] = vq[KMAX - 1];
        }
    }
    // 16 utterance (query) rows of this segment owned by this row group.
    {
        const int r0 = RC_ROWS + SEG * i + rg * 16;
        for (int rr = 0; rr < 16; ++rr) {
            int* __restrict__ rowp = p + (size_t)(r0 + rr) * W;
#pragma unroll
            for (int k = 0; k < KMAX - 1; ++k) rowp[k << 8] = vq[k];
            if (has_tail) rowp[(KMAX - 1) << 8] = vq[KMAX - 1];
        }
    }
    // Summary row (one per segment) — written by row group 0 only.
    if (rg == 0) {
        int* __restrict__ rowp = p + (size_t)(SUM_BASE + i) * W;
#pragma unroll
        for (int k = 0; k < KMAX - 1; ++k) rowp[k << 8] = vs[k];
        if (has_tail) rowp[(KMAX - 1) << 8] = vs[KMAX - 1];
    }
}

extern "C" void kernel_launch(void* const* d_in, const int* in_sizes, int n_in,
                              void* d_out, int out_size, void* d_ws, size_t ws_size,
                              hipStream_t stream) {
    (void)d_in; (void)in_sizes; (void)n_in; (void)d_ws; (void)ws_size; (void)out_size;
    emformer_mask_kernel<<<dim3(ROW_GROUPS, COL_TILES, NSEG), dim3(256), 0, stream>>>(
        (int*)d_out);
}

// Round 2
// 438.421 us; speedup vs baseline: 1.1019x; 1.1019x over previous
//
#include <hip/hip_runtime.h>

// Emformer mask materialization — LDS byte-image + flat aligned dwordx4 replication.
//
// R1 post-mortem: 4 B/lane stores with block-tiled rows ran at 2.1 TB/s (200 us)
// vs the flat 16 B/lane kernel's 3.0 TB/s (141 us). Store pattern, not ALU, is
// the limiter. This version keeps the PROVEN flat, 16B-aligned dwordx4 store
// stream and removes the VALU cost: per segment, all 32 RC rows and all 128
// utterance rows share one row image (summary row a second image). Both are
// built once per block as BYTE images in LDS; the store loop fetches 4 values
// with two conflict-free ds_read_b32 + a 64-bit funnel shift (~13 VALU / 16 B
// vs ~60 in the 141 us kernel).
//
// Output int32: 1 = attention disallowed, 0 = allowed.
namespace {
constexpr int SEG  = 128;
constexpr int RCL  = 32;
constexpr int LC   = 64;
constexpr int MEM  = 4;
constexpr int NSEG = 64;
constexpr int U    = NSEG * SEG;                    // 8192
constexpr int W    = (NSEG - 1) + RCL * NSEG + U;   // 10303
constexpr int RC_ROWS  = RCL * NSEG;                // 2048
constexpr int UTT_BASE = (NSEG - 1) + RCL * NSEG;   // 2111
constexpr int W_PAD = 10312;                        // W + 8 wrap bytes, 8-aligned

// Per-segment virtual int ranges (band-concatenated):
//   [0, C0):        32 RC rows   (image Q), rows 32*i ..
//   [C0, C1):       128 Q rows   (image Q), rows 2048 + 128*i ..
//   [C1, C2):       1 summary row (image S), row 10240 + i
constexpr unsigned C0 = 32u * W;          // 329,696
constexpr unsigned C1 = 160u * W;         // 1,648,480
constexpr unsigned C2 = 161u * W;         // 1,658,783
constexpr int P = 24;                     // slices per segment -> 1536 blocks, 6/CU
constexpr unsigned PER = (C2 + P - 1) / P;  // 69,117 ints per slice
}

typedef int i32x4 __attribute__((ext_vector_type(4)));

// Stream flat int range [f0, f1) of one band. Column of flat index f is
// (f - rbaseW) % W; all rows in the band share byte image `img` (img[W..W+7]
// replicates img[0..7] so a 4-int vector crossing a row boundary reads the
// next row's leading columns).
__device__ __forceinline__ void do_piece(const unsigned char* __restrict__ img,
                                         int* __restrict__ out,
                                         unsigned f0, unsigned f1,
                                         unsigned rbaseW, int tid) {
    const unsigned fa = (f0 + 3u) & ~3u;   // first aligned int
    const unsigned fe = f1 & ~3u;          // aligned end
    if (fa >= fe) {                        // degenerate tiny piece
        for (unsigned f = f0 + (unsigned)tid; f < f1; f += 256u)
            out[f] = (int)img[(f - rbaseW) % (unsigned)W];
        return;
    }
    // head [f0, fa) and tail [fe, f1): <4 ints each, scalar stores.
    if ((unsigned)tid < fa - f0) {
        unsigned f = f0 + (unsigned)tid;
        out[f] = (int)img[(f - rbaseW) % (unsigned)W];
    }
    if ((unsigned)tid < f1 - fe) {
        unsigned f = fe + (unsigned)tid;
        out[f] = (int)img[(f - rbaseW) % (unsigned)W];
    }
    // body: one i32x4 per thread per iteration, 1 KiB per wave instruction.
    const unsigned qa = fa >> 2, qe = fe >> 2;
    unsigned c = (fa + 4u * (unsigned)tid - rbaseW) % (unsigned)W;  // column
    const unsigned* __restrict__ im32 = (const unsigned*)img;
    i32x4* __restrict__ o = (i32x4*)out + qa + (unsigned)tid;
    for (unsigned q = qa + (unsigned)tid; q < qe; q += 256u, o += 256) {
        const unsigned wc = c >> 2;
        const unsigned sh = (c & 3u) * 8u;
        const unsigned w0 = im32[wc];
        const unsigned w1 = im32[wc + 1];   // safe: wc+1 <= (W-1)/4+1, padded
        const unsigned packed =
            (unsigned)(((((unsigned long long)w1) << 32) | w0) >> sh);
        i32x4 v;
        v.x = (int)(packed & 0xffu);
        v.y = (int)((packed >> 8) & 0xffu);
        v.z = (int)((packed >> 16) & 0xffu);
        v.w = (int)(packed >> 24);
        *o = v;
        c += 1024u;
        if (c >= (unsigned)W) c -= (unsigned)W;
    }
}

__global__ __launch_bounds__(256) void emformer_mask_kernel(int* __restrict__ out) {
    __shared__ __align__(16) unsigned char s_img[2][W_PAD];
    const int tid = (int)threadIdx.x;
    const int b   = (int)blockIdx.x;   // slice 0..P-1
    const int i   = (int)blockIdx.y;   // segment 0..63

    // Allowed-column intervals for segment i.
    const int a0 = max(i - MEM, 0);                   // memory slots [a0, a1)
    const int a1 = i;
    const int b0 = (NSEG - 1) + RCL * i;              // own right-context
    const int d0 = UTT_BASE + max(SEG * i - LC, 0);   // own segment + left ctx
    const int d1 = UTT_BASE + SEG * (i + 1);

    // Build both byte images (Q rows and summary row).
    for (int c = tid; c < W; c += 256) {
        const bool inA = (unsigned)(c - a0) < (unsigned)(a1 - a0);
        const bool inB = (unsigned)(c - b0) < (unsigned)RCL;
        const bool inD = (unsigned)(c - d0) < (unsigned)(d1 - d0);
        s_img[0][c] = (inA | inB | inD) ? 0 : 1;   // logical_not(allowed)
        s_img[1][c] = (inA | inD) ? 0 : 1;
    }
    if (tid < 8) {                                  // row-wrap replication
        s_img[0][W + tid] = s_img[0][tid];          // (own writes: no race)
        s_img[1][W + tid] = s_img[1][tid];
    }
    __syncthreads();

    // This block's virtual int range within segment i.
    const unsigned v0 = (unsigned)b * PER;
    const unsigned v1 = min(v0 + PER, C2);

    // Band 0: RC rows.
    if (v0 < C0) {
        const unsigned rbW = (unsigned)(RCL * i) * (unsigned)W;
        do_piece(s_img[0], out, rbW + v0, rbW + min(v1, C0), rbW, tid);
    }
    // Band 1: utterance rows.
    if (v1 > C0 && v0 < C1) {
        const unsigned s = max(v0, C0), e = min(v1, C1);
        const unsigned rbW = (unsigned)(RC_ROWS + SEG * i) * (unsigned)W;
        do_piece(s_img[0], out, rbW + (s - C0), rbW + (e - C0), rbW, tid);
    }
    // Band 2: summary row.
    if (v1 > C1) {
        const unsigned s = max(v0, C1);
        const unsigned rbW = (unsigned)(RC_ROWS + U + i) * (unsigned)W;
        do_piece(s_img[1], out, rbW + (s - C1), rbW + (v1 - C1), rbW, tid);
    }
}

extern "C" void kernel_launch(void* const* d_in, const int* in_sizes, int n_in,
                              void* d_out, int out_size, void* d_ws, size_t ws_size,
                              hipStream_t stream) {
    (void)d_in; (void)in_sizes; (void)n_in; (void)d_ws; (void)ws_size; (void)out_size;
    emformer_mask_kernel<<<dim3(P, NSEG), dim3(256), 0, stream>>>((int*)d_out);
}

// Round 3
// 428.644 us; speedup vs baseline: 1.1271x; 1.0228x over previous
//
#include <hip/hip_runtime.h>

// Emformer mask materialization — memset-1 + sparse-zero version.
//
// R0-R2 post-mortem: three structurally different hand-written store kernels
// (flat dwordx4 / 4B replicate / LDS-image dwordx4) all plateau at 2.1-3.0 TB/s
// of pure writes, while the rocclr fillBufferAligned dispatch in the SAME timed
// graph sustains 6.2 TB/s. A 4x reduction in VALU-per-byte moved perf only 15%,
// so the cap is not compute. Instead of fighting it: the output is ~97.8% ones
// (only ~228 of 10303 columns per row are 0), so
//   1) hipMemsetD32Async(out, 1, ...)  -> runtime's fillBufferAligned path,
//      424.6 MB at its demonstrated ~6.2 TB/s (~70-80 us);
//   2) a tiny kernel writes the <=228 zero ints per row (~9.4 MB, ~5-10 us).
//
// Output int32: 1 = attention disallowed, 0 = allowed.
namespace {
constexpr int SEG  = 128;   // segment_length
constexpr int RCL  = 32;    // right_context_length
constexpr int LC   = 64;    // left_context_length
constexpr int MEM  = 4;     // max_memory_length
constexpr int NSEG = 64;    // num_segments
constexpr int U    = NSEG * SEG;                    // 8192
constexpr int W    = (NSEG - 1) + RCL * NSEG + U;   // 10303 (mask width)
constexpr int RC_ROWS  = RCL * NSEG;                // 2048
constexpr int Q_ROWS   = U;                         // 8192
constexpr int ROWS     = RC_ROWS + Q_ROWS + NSEG;   // 10304
constexpr int UTT_BASE = (NSEG - 1) + RCL * NSEG;   // 2111
constexpr size_t TOTAL = (size_t)ROWS * (size_t)W;  // 106,162,112 int32 words
}

// One block per output row. Writes 0 to the allowed-column intervals:
//   A: [a0, i)               memory slots      (width <= 4)
//   B: [b0, b0+32)           own right-context (query rows only)
//   D: [d0, d0+wD)           own segment + left context (width <= 192)
// All three are lane-contiguous dword stores (full 256B wave segments for D).
__global__ __launch_bounds__(256) void emformer_zero_kernel(int* __restrict__ out) {
    const int r = (int)blockIdx.x;
    const int t = (int)threadIdx.x;

    int i;
    bool is_summary = false;
    if (r < RC_ROWS) {
        i = r >> 5;                    // / RCL
    } else if (r < RC_ROWS + Q_ROWS) {
        i = (r - RC_ROWS) >> 7;        // / SEG
    } else {
        i = r - (RC_ROWS + Q_ROWS);
        is_summary = true;
    }

    const int a0  = max(i - MEM, 0);
    const int wA  = i - a0;                         // 0..4
    const int b0  = (NSEG - 1) + RCL * i;           // own right-context start
    const int d0s = max(SEG * i - LC, 0);
    const int d0  = UTT_BASE + d0s;
    const int wD  = SEG * (i + 1) - d0s;            // 128 (i=0) or 192

    int* __restrict__ row = out + (size_t)r * (size_t)W;
    if (t < wA)                row[a0 + t] = 0;
    if (!is_summary && t < RCL) row[b0 + t] = 0;
    if (t < wD)                row[d0 + t] = 0;
}

extern "C" void kernel_launch(void* const* d_in, const int* in_sizes, int n_in,
                              void* d_out, int out_size, void* d_ws, size_t ws_size,
                              hipStream_t stream) {
    (void)d_in; (void)in_sizes; (void)n_in; (void)d_ws; (void)ws_size; (void)out_size;
    // Fill entire mask with 1 (disallowed) via the runtime's fast fill path.
    (void)hipMemsetD32Async((hipDeviceptr_t)d_out, 1, TOTAL, stream);
    // Then carve out the allowed (0) intervals — ~2.2% of the buffer.
    emformer_zero_kernel<<<dim3(ROWS), dim3(256), 0, stream>>>((int*)d_out);
}